// Round 4
// baseline (68313.483 us; speedup 1.0000x reference)
//
#include <hip/hip_runtime.h>
#include <math.h>

#define Bn 512
#define Tn 256
#define Hn 512
#define Vn 7
#define BH (Bn*Hn)          // 262144
#define NLP (Bn*Tn*Vn)      // 917504

#define NBLK 256
#define NTHR 512
#define NGRP 16             // independent batch-row groups (32 b each)
#define GBLK 16             // blocks per group (j-tiles)
#define CNT_STRIDE 32       // ints; 128B per counter line

#define ASTR 516            // A_lds row stride (516%32==4 -> conflict-free frag reads)
#define LDW 68              // red-buffer row stride (frozen from R1-R3)
#define SHN 17408           // union: A tile (32*ASTR<=16512) / red (256*68=17408)

// Round-12: W-in-registers. R3's tell fired (VGPR stayed 128 -> compiler
// re-sank the upfront loads; overlap never happened). New model: LDS pipe
// (2048 wave-b128/step) ~10us > VALU FMA 6.8us; W is half the reads and all
// of the staging. W slice per thread = 8jg x 64k = 512 floats = 128 VGPR =
// exactly our spare budget. W is loaded ONCE at t=0 (float2 pair-packed);
// per step only A (64KB) is staged, in one burst, into a buffer that is
// reused as the K-combine red buffer. Barriers 11->7/step. GEMM is fully
// unrolled (register-static W indexing); to stay under the 32KB I$ the FMAs
// are 2048 v_pk_fma_f32 (elementwise_fma on float2, packed across ji-pairs).
// Per-cell accumulation order (c->q->kk) and K-combine/epilogue trees are
// BITWISE IDENTICAL to R3: absmax should be exactly 0.0234375.

typedef float f2 __attribute__((ext_vector_type(2)));

__device__ __forceinline__ float sigf(float x){ return 1.0f/(1.0f + expf(-x)); }

__device__ __forceinline__ void group_barrier(int* cnt, int target){
    __syncthreads();
    if (threadIdx.x == 0){
        __hip_atomic_fetch_add(cnt, 1, __ATOMIC_RELEASE, __HIP_MEMORY_SCOPE_AGENT);
        while (__hip_atomic_load(cnt, __ATOMIC_RELAXED, __HIP_MEMORY_SCOPE_AGENT) < target)
            __builtin_amdgcn_s_sleep(1);
        (void)__hip_atomic_load(cnt, __ATOMIC_ACQUIRE, __HIP_MEMORY_SCOPE_AGENT);
    }
    __syncthreads();
}

__global__ void init_kernel(float* lp, int* cnts){
    int i = blockIdx.x*blockDim.x + threadIdx.x;
    if (i < NGRP) cnts[i*CNT_STRIDE] = 0;
    for (int x = i; x < NLP; x += (int)(gridDim.x*blockDim.x)) lp[x] = 0.0f;
}

__global__ void __launch_bounds__(NTHR, 2)
decoder_rnn_kernel(const float* __restrict__ h0, const float* __restrict__ c0,
                   const float* __restrict__ tgt, const float* __restrict__ Wih,
                   const float* __restrict__ Whh, const float* __restrict__ bih,
                   const float* __restrict__ bhh, const float* __restrict__ Wout,
                   const float* __restrict__ bout, float* out, float* ws)
{
    __shared__ float shbuf[SHN];          // A tile (stride ASTR) / red (stride LDW)
    __shared__ float hn_lds[32*33];
    __shared__ int   idx_lds[32];

    float* hbuf = ws;                  // 2*BH ping-pong h
    float* cws  = ws + 2*BH;           // BH c-state
    int*   cnts = (int*)(ws + 3*BH);   // NGRP padded counters
    float* lp   = out;                 // logits -> logp in place

    const int bt = blockIdx.x & 15;    // group: all 16 j-blocks of bt share an XCD
    const int jt = blockIdx.x >> 4;
    const int b0 = bt << 5;
    const int j0 = jt << 5;

    const int tid = threadIdx.x;
    const int kq  = tid >> 6;          // wave id = K slice (k-offset kq*8 within chunk)
    const int l   = tid & 63;
    const int bq  = l >> 4;            // 0..3  : b = bq + 4*bi
    const int jq  = l & 15;            // 0..15 : jg = jq + 16*ji
    int* cnt = cnts + bt*CNT_STRIDE;

    const int gtid = blockIdx.x*NTHR + threadIdx.x;
    const int nthr = NBLK*NTHR;
    const int lg_bl = tid / 7;         // logits-phase indices (hoisted)
    const int lg_v  = tid % 7;

    // ---- W slice -> registers, once. Pair-packed: Wp[c][kk8][p] =
    //      (Whh[gate p][j0+jq][k], Whh[gate p][j0+16+jq][k]),
    //      k = c*64 + kq*8 + kk8. ji=2p <-> col jq, ji=2p+1 <-> col 16+jq,
    //      identical cell mapping to R3 (gi=ji>>1, jj=16*(ji&1)+jq). ----
    f2 Wp[8][8][4];
    #pragma unroll
    for (int p = 0; p < 4; ++p){
        const long rA = (long)((p << 9) + j0 + jq) * Hn;
        const long rB = rA + (long)16 * Hn;
        #pragma unroll
        for (int c = 0; c < 8; ++c){
            const int k = (c << 6) + (kq << 3);
            const float4 a0 = *(const float4*)(Whh + rA + k);
            const float4 a1 = *(const float4*)(Whh + rA + k + 4);
            const float4 e0 = *(const float4*)(Whh + rB + k);
            const float4 e1 = *(const float4*)(Whh + rB + k + 4);
            Wp[c][0][p] = f2{a0.x, e0.x}; Wp[c][1][p] = f2{a0.y, e0.y};
            Wp[c][2][p] = f2{a0.z, e0.z}; Wp[c][3][p] = f2{a0.w, e0.w};
            Wp[c][4][p] = f2{a1.x, e1.x}; Wp[c][5][p] = f2{a1.y, e1.y};
            Wp[c][6][p] = f2{a1.z, e1.z}; Wp[c][7][p] = f2{a1.w, e1.w};
        }
    }

    // ---- per-block state init (verbatim) ----
    #pragma unroll
    for (int i = 0; i < 8; ++i){
        const int f = tid + (i << 9);
        const int r = f >> 7, c4 = f & 127;
        *(float4*)(hbuf + (long)(b0 + r)*Hn + (c4 << 2)) =
            *(const float4*)(h0 + (long)(b0 + r)*Hn + (c4 << 2));
    }
    if (tid < 256){
        const int r = tid >> 3, c4 = tid & 7;
        *(float4*)(cws + (long)(b0 + r)*Hn + j0 + (c4 << 2)) =
            *(const float4*)(c0 + (long)(b0 + r)*Hn + j0 + (c4 << 2));
    }
    __syncthreads();

    for (int t = 0; t < Tn; ++t){
        const float* hprev = hbuf + (t & 1)*BH;
        float*       hnext = hbuf + ((t + 1) & 1)*BH;

        // ---- issue the A-tile global loads first (hide under argmax) ----
        float4 sreg[8];
        #pragma unroll
        for (int i = 0; i < 8; ++i){
            const int f = tid + (i << 9);
            const int r = f >> 7, c4 = f & 127;
            sreg[i] = *(const float4*)(hprev + (long)(b0 + r)*Hn + (c4 << 2));
        }

        // ---- argmax -> one-hot index (frozen) ----
        if (tid < 32){
            const int  bl = tid;
            const long b  = b0 + bl;
            float best; int am = 0;
            if (t == 0){
                const float* xp = tgt + (b*Tn)*Vn;
                best = xp[0];
                #pragma unroll
                for (int v = 1; v < Vn; ++v){ float xv = xp[v]; if (xv > best){ best = xv; am = v; } }
            } else {
                const float* xp = lp + (b*Tn + (t-1))*Vn;
                best = xp[0] + bout[0];
                #pragma unroll
                for (int v = 1; v < Vn; ++v){ float xv = xp[v] + bout[v]; if (xv > best){ best = xv; am = v; } }
            }
            idx_lds[bl] = am;
        }

        // ---- A tile -> LDS, one burst ----
        #pragma unroll
        for (int i = 0; i < 8; ++i){
            const int f = tid + (i << 9);
            const int r = f >> 7, c4 = f & 127;
            *(float4*)(&shbuf[r*ASTR + (c4 << 2)]) = sreg[i];
        }
        __syncthreads();

        // ---- GEMM: W from registers, A from LDS (broadcast, conflict-free),
        //      no barriers. Per-cell k-order c->q->kk == R3 (bitwise). ----
        f2 acc2[8][4];
        #pragma unroll
        for (int a = 0; a < 8; ++a)
            #pragma unroll
            for (int p = 0; p < 4; ++p) acc2[a][p] = f2{0.0f, 0.0f};

        #pragma unroll
        for (int c = 0; c < 8; ++c){
            const int kb = (c << 6) + (kq << 3);
            #pragma unroll
            for (int q = 0; q < 2; ++q){
                float4 av[8];
                #pragma unroll
                for (int bi = 0; bi < 8; ++bi)
                    av[bi] = *(const float4*)(&shbuf[(bq + 4*bi)*ASTR + kb + (q << 2)]);
                #pragma unroll
                for (int bi = 0; bi < 8; ++bi){
                    #pragma unroll
                    for (int kk = 0; kk < 4; ++kk){
                        const float a = ((const float*)&av[bi])[kk];
                        const f2 as = {a, a};
                        #pragma unroll
                        for (int p = 0; p < 4; ++p)
                            acc2[bi][p] = __builtin_elementwise_fma(as, Wp[c][(q << 2) + kk][p], acc2[bi][p]);
                    }
                }
            }
        }
        __syncthreads();   // A reads done before red overwrites shbuf

        // ---- K-combine: fold 8 wave-slices -> 4 (red layout frozen) ----
        float* red = &shbuf[0];
        if (kq >= 4){
            float* p_ = red + ((kq - 4)*64 + l)*LDW;
            #pragma unroll
            for (int bi = 0; bi < 8; ++bi){
                *(float4*)(p_ + (bi << 3))     = make_float4(acc2[bi][0].x, acc2[bi][0].y, acc2[bi][1].x, acc2[bi][1].y);
                *(float4*)(p_ + (bi << 3) + 4) = make_float4(acc2[bi][2].x, acc2[bi][2].y, acc2[bi][3].x, acc2[bi][3].y);
            }
        }
        __syncthreads();
        if (kq < 4){
            float* p_ = red + (kq*64 + l)*LDW;
            #pragma unroll
            for (int bi = 0; bi < 8; ++bi){
                float4 r0 = *(const float4*)(p_ + (bi << 3));
                float4 r1 = *(const float4*)(p_ + (bi << 3) + 4);
                acc2[bi][0].x += r0.x; acc2[bi][0].y += r0.y; acc2[bi][1].x += r0.z; acc2[bi][1].y += r0.w;
                acc2[bi][2].x += r1.x; acc2[bi][2].y += r1.y; acc2[bi][3].x += r1.z; acc2[bi][3].y += r1.w;
            }
            #pragma unroll
            for (int bi = 0; bi < 8; ++bi){
                *(float4*)(p_ + (bi << 3))     = make_float4(acc2[bi][0].x, acc2[bi][0].y, acc2[bi][1].x, acc2[bi][1].y);
                *(float4*)(p_ + (bi << 3) + 4) = make_float4(acc2[bi][2].x, acc2[bi][2].y, acc2[bi][3].x, acc2[bi][3].y);
            }
        }
        __syncthreads();

        // ---- epilogue: all 512 threads, 2 cells each (expressions frozen) ----
        {
            const int b  = tid >> 4;           // 0..31
            const int jp = tid & 15;
            const int ix = idx_lds[b];
            #pragma unroll
            for (int u = 0; u < 2; ++u){
                const int j  = (jp << 1) + u;                     // 0..31
                const int lo = ((b & 3) << 4) + (j & 15);         // owner lane
                const int vb = ((b >> 2) << 3) + (j >> 4);        // bi*8 + (j>>4)
                float g4[4];
                #pragma unroll
                for (int g = 0; g < 4; ++g){
                    const int v = vb + (g << 1);                  // + ji gate part
                    float s  = red[(      lo)*LDW + v];
                    s       += red[( 64 + lo)*LDW + v];
                    s       += red[(128 + lo)*LDW + v];
                    s       += red[(192 + lo)*LDW + v];
                    const int r = (g << 9) + j0 + j;
                    g4[g] = s + (Wih[r*Vn + ix] + bih[r] + bhh[r]);
                }
                const long bg = b0 + b;
                const int  jj = j0 + j;
                const float iv = sigf(g4[0]);
                const float fv = sigf(g4[1]);
                const float gv = tanhf(g4[2]);
                const float ov = sigf(g4[3]);
                const float cold = cws[bg*Hn + jj];
                const float cn2 = fv*cold + iv*gv;
                cws[bg*Hn + jj] = cn2;
                const float hn = ov * tanhf(cn2);
                hnext[bg*Hn + jj] = hn;
                hn_lds[b*33 + j] = hn;
            }
        }
        __syncthreads();

        // ---- partial logits (frozen) ----
        if (tid < 224){
            const float* wo = Wout + lg_v*Hn + j0;
            float s = 0.0f;
            #pragma unroll
            for (int jj = 0; jj < 32; ++jj)
                s = fmaf(hn_lds[lg_bl*33 + jj], wo[jj], s);
            atomicAdd(&lp[((long)(b0 + lg_bl)*Tn + t)*Vn + lg_v], s);
        }

        group_barrier(cnt, GBLK*(t+1));
    }

    // ---- final: hT, cT, in-place log_softmax (frozen) ----
    for (int i = gtid; i < BH; i += nthr){
        out[NLP + i]      = hbuf[i];   // T=256 even -> final h in buffer 0
        out[NLP + BH + i] = cws[i];
    }
    {
        const long row = gtid;         // exactly B*T rows
        float x[Vn]; float m = -INFINITY;
        #pragma unroll
        for (int v = 0; v < Vn; ++v){ x[v] = lp[row*Vn + v] + bout[v]; m = fmaxf(m, x[v]); }
        float s = 0.0f;
        #pragma unroll
        for (int v = 0; v < Vn; ++v) s += expf(x[v] - m);
        const float ls = logf(s);
        #pragma unroll
        for (int v = 0; v < Vn; ++v) lp[row*Vn + v] = x[v] - m - ls;
    }
}

extern "C" void kernel_launch(void* const* d_in, const int* in_sizes, int n_in,
                              void* d_out, int out_size, void* d_ws, size_t ws_size,
                              hipStream_t stream) {
    const float* h0   = (const float*)d_in[0];
    const float* c0   = (const float*)d_in[1];
    const float* tgt  = (const float*)d_in[2];
    const float* Wih  = (const float*)d_in[3];
    const float* Whh  = (const float*)d_in[4];
    const float* bih  = (const float*)d_in[5];
    const float* bhh  = (const float*)d_in[6];
    const float* Wout = (const float*)d_in[7];
    const float* bout = (const float*)d_in[8];
    float* out = (float*)d_out;
    float* ws  = (float*)d_ws;               // 3*BH floats + counters
    int*   cnts = (int*)(ws + 3*BH);

    init_kernel<<<256, 256, 0, stream>>>(out, cnts);

    void* args[] = { &h0, &c0, &tgt, &Wih, &Whh, &bih, &bhh, &Wout, &bout, &out, &ws };
    (void)hipLaunchCooperativeKernel((const void*)decoder_rnn_kernel,
                               dim3(NBLK), dim3(NTHR), args, 0, stream);
}

// Round 8
// 8382.895 us; speedup vs baseline: 8.1492x; 8.1492x over previous
//
#include <hip/hip_runtime.h>
#include <math.h>

#define Bn 512
#define Tn 256
#define Hn 512
#define Vn 7
#define BH (Bn*Hn)          // 262144
#define NLP (Bn*Tn*Vn)      // 917504

#define NBLK 512            // 2 blocks/CU: two independent barrier domains
#define NTHR 256
#define NGRP 32             // groups = 16 batch rows each
#define GBLK 16             // blocks per group (j-tiles of width 32)
#define CNT_STRIDE 16       // ints; 32 counters = 2KB ws footprint

#define LDW 68              // row stride (64 k + 4 pad; 68%32==4)
#define WBUF (64*LDW)       // 4352 floats: 64 gate-rows x 64 k (half-panel)
#define ABUF (16*LDW)       // 1088 floats: 16 b x 64 k
#define SHN (2*WBUF + 2*ABUF)  // 10880 floats = 43.5KB
#define RSLICE (32*LDW)     // K-combine slice; 4*RSLICE=8704 overlays W bufs

// Round-16: R5/R6/R7 never RAN - JSON absmax 468 = max|ref_cT| = zeroed out
// buffer: hipLaunchCooperativeKernel rejects 512-block grids on this stack
// (256 was fine R0-R3) and we discarded the error. Our sync is hand-rolled
// atomic counters -> cooperative launch is unnecessary: NORMAL launch, 512
// blocks at rock-solid 2/CU static occupancy (LDS 44.6KB, ~130 VGPR, 8
// waves/CU) -> all resident. Also fixed a real cross-XCD hazard found in
// audit: finale is now GROUP-LOCAL (block (g,jt) finalizes batch row
// b0p+jt, same XCD as its writers, synced by the last group barrier) and
// the 32-group global wait is deleted. Everything else identical to R7
// (R3-bitwise GEMM/fold/epilogue/logits).

__device__ __forceinline__ float sigf(float x){ return 1.0f/(1.0f + expf(-x)); }

__device__ __forceinline__ void group_barrier(int* cnt, int target){
    __syncthreads();
    if (threadIdx.x == 0){
        __hip_atomic_fetch_add(cnt, 1, __ATOMIC_RELEASE, __HIP_MEMORY_SCOPE_AGENT);
        while (__hip_atomic_load(cnt, __ATOMIC_RELAXED, __HIP_MEMORY_SCOPE_AGENT) < target)
            __builtin_amdgcn_s_sleep(1);
        (void)__hip_atomic_load(cnt, __ATOMIC_ACQUIRE, __HIP_MEMORY_SCOPE_AGENT);
    }
    __syncthreads();
}

__global__ void init_kernel(float* lp, int* cnts){
    int i = blockIdx.x*blockDim.x + threadIdx.x;
    if (i < NGRP) cnts[i*CNT_STRIDE] = 0;
    for (int x = i; x < NLP; x += (int)(gridDim.x*blockDim.x)) lp[x] = 0.0f;
}

__global__ void __launch_bounds__(NTHR, 2)
decoder_rnn_kernel(const float* __restrict__ h0, const float* __restrict__ c0,
                   const float* __restrict__ tgt, const float* __restrict__ Wih,
                   const float* __restrict__ Whh, const float* __restrict__ bih,
                   const float* __restrict__ bhh, const float* __restrict__ Wout,
                   const float* __restrict__ bout, float* out, float* ws)
{
    __shared__ float sh[SHN];          // W dbuf (2x64rows) | A dbuf ; red overlays
    __shared__ float hn_lds[16*33];
    __shared__ int   idx_lds[16];

    float* hbuf = ws;                  // 2*BH ping-pong h
    float* cws  = ws + 2*BH;           // BH c-state
    int*   cnts = (int*)(ws + 3*BH);   // NGRP compact counters
    float* lp   = out;                 // logits -> logp in place

    const int g   = blockIdx.x & 31;   // group: 16 batch rows; same-XCD (step 32)
    const int jt  = blockIdx.x >> 5;   // 0..15 j-tiles of width 32
    const int b0p = g << 4;
    const int j0  = jt << 5;

    const int tid = threadIdx.x;
    const int kq  = tid >> 5;          // K slice 0..7 (k-offset kq*8 per 64-chunk)
    const int l5  = tid & 31;
    const int bq  = l5 >> 4;           // 0..1 : b = bq + 2*bi
    const int jq  = l5 & 15;           // 0..15: row_full = jq + 16*ri
    int* cnt = cnts + g*CNT_STRIDE;

    const int lg_bl = tid / 7, lg_v = tid % 7;

    // ---- t-invariant staging offsets ----
    int wgoff[2][4], wloff[4];
    #pragma unroll
    for (int i = 0; i < 4; ++i){
        const int f = tid + (i << 8);
        const int sr = f >> 4, sc = f & 15;       // half-panel row 0..63, k-quad
        wloff[i] = sr*LDW + (sc << 2);
        #pragma unroll
        for (int h = 0; h < 2; ++h){
            const int rf = (h << 6) + sr;         // full row 0..127
            wgoff[h][i] = (((rf >> 5) << 9) + j0 + (rf & 31))*Hn + (sc << 2);
        }
    }
    const int agoff = (b0p + (tid >> 4))*Hn + ((tid & 15) << 2);
    const int aloff = (tid >> 4)*LDW + ((tid & 15) << 2);
    const int afb = bq*LDW + (kq << 3);           // A frag base
    const int wfb = jq*LDW + (kq << 3);           // W frag base

    // ---- per-block state init (group rows duplicated across jt: benign) ----
    #pragma unroll
    for (int i = 0; i < 8; ++i){
        const int f = tid + (i << 8);
        const int r = f >> 7, c4 = f & 127;       // 16 rows x 128 quads
        *(float4*)(hbuf + (long)(b0p + r)*Hn + (c4 << 2)) =
            *(const float4*)(h0 + (long)(b0p + r)*Hn + (c4 << 2));
    }
    if (tid < 128){
        const int r = tid >> 3, c4 = tid & 7;     // 16 rows x 8 quads (32 cols)
        *(float4*)(cws + (long)(b0p + r)*Hn + j0 + (c4 << 2)) =
            *(const float4*)(c0 + (long)(b0p + r)*Hn + j0 + (c4 << 2));
    }
    __syncthreads();

    for (int t = 0; t < Tn; ++t){
        const float* hprev = hbuf + (t & 1)*BH;
        float*       hnext = hbuf + ((t + 1) & 1)*BH;

        // ---- prologue: W(0,h0) + A[0] loads ----
        float4 wreg[4], areg;
        #pragma unroll
        for (int i = 0; i < 4; ++i) wreg[i] = *(const float4*)(Whh + wgoff[0][i]);
        areg = *(const float4*)(hprev + agoff);

        // ---- argmax -> one-hot index (frozen expr) ----
        if (tid < 16){
            const long b = b0p + tid;
            float best; int am = 0;
            if (t == 0){
                const float* xp = tgt + (b*Tn)*Vn;
                best = xp[0];
                #pragma unroll
                for (int v = 1; v < Vn; ++v){ float xv = xp[v]; if (xv > best){ best = xv; am = v; } }
            } else {
                const float* xp = lp + (b*Tn + (t-1))*Vn;
                best = xp[0] + bout[0];
                #pragma unroll
                for (int v = 1; v < Vn; ++v){ float xv = xp[v] + bout[v]; if (xv > best){ best = xv; am = v; } }
            }
            idx_lds[tid] = am;
        }

        #pragma unroll
        for (int i = 0; i < 4; ++i) *(float4*)(&sh[wloff[i]]) = wreg[i];   // buf0
        *(float4*)(&sh[2*WBUF + aloff]) = areg;                            // A par0
        __syncthreads();

        float acc0[8][4], acc1[8][4];   // cells ri=0..3 / ri=4..7 (static idx!)
        #pragma unroll
        for (int a = 0; a < 8; ++a)
            #pragma unroll
            for (int r_ = 0; r_ < 4; ++r_){ acc0[a][r_] = 0.0f; acc1[a][r_] = 0.0f; }

        // ---- GEMM: 8 chunks x 2 half-panels, dbuf, 2 barriers/chunk ----
        #pragma unroll 1
        for (int c = 0; c < 8; ++c){
            // == half 0: compute W(c,h0)[buf0] x A[c]; stage W(c,h1)->buf1 ==
            #pragma unroll
            for (int i = 0; i < 4; ++i)
                wreg[i] = *(const float4*)(Whh + wgoff[1][i] + (c << 6));
            {
                const float* Wb = sh + wfb;
                const float* Ab = sh + 2*WBUF + (c & 1)*ABUF + afb;
                #pragma unroll
                for (int q = 0; q < 2; ++q){
                    float4 wv[4];
                    #pragma unroll
                    for (int rl = 0; rl < 4; ++rl)
                        wv[rl] = *(const float4*)(Wb + rl*(16*LDW) + (q << 2));
                    #pragma unroll
                    for (int bi = 0; bi < 8; ++bi){
                        const float4 av = *(const float4*)(Ab + bi*(2*LDW) + (q << 2));
                        #pragma unroll
                        for (int rl = 0; rl < 4; ++rl){
                            float s = acc0[bi][rl];
                            s = fmaf(av.x, wv[rl].x, s);
                            s = fmaf(av.y, wv[rl].y, s);
                            s = fmaf(av.z, wv[rl].z, s);
                            s = fmaf(av.w, wv[rl].w, s);
                            acc0[bi][rl] = s;
                        }
                    }
                }
            }
            #pragma unroll
            for (int i = 0; i < 4; ++i) *(float4*)(&sh[WBUF + wloff[i]]) = wreg[i];
            __syncthreads();

            // == half 1: compute W(c,h1)[buf1]; stage W(c+1,h0)->buf0, A[c+1] ==
            const int cn = (c < 7) ? (c + 1) : 7;   // clamp: identical-byte rewrite
            #pragma unroll
            for (int i = 0; i < 4; ++i)
                wreg[i] = *(const float4*)(Whh + wgoff[0][i] + (cn << 6));
            areg = *(const float4*)(hprev + agoff + (cn << 6));
            {
                const float* Wb = sh + WBUF + wfb;
                const float* Ab = sh + 2*WBUF + (c & 1)*ABUF + afb;
                #pragma unroll
                for (int q = 0; q < 2; ++q){
                    float4 wv[4];
                    #pragma unroll
                    for (int rl = 0; rl < 4; ++rl)
                        wv[rl] = *(const float4*)(Wb + rl*(16*LDW) + (q << 2));
                    #pragma unroll
                    for (int bi = 0; bi < 8; ++bi){
                        const float4 av = *(const float4*)(Ab + bi*(2*LDW) + (q << 2));
                        #pragma unroll
                        for (int rl = 0; rl < 4; ++rl){
                            float s = acc1[bi][rl];
                            s = fmaf(av.x, wv[rl].x, s);
                            s = fmaf(av.y, wv[rl].y, s);
                            s = fmaf(av.z, wv[rl].z, s);
                            s = fmaf(av.w, wv[rl].w, s);
                            acc1[bi][rl] = s;
                        }
                    }
                }
            }
            #pragma unroll
            for (int i = 0; i < 4; ++i) *(float4*)(&sh[wloff[i]]) = wreg[i];   // buf0
            *(float4*)(&sh[2*WBUF + (cn & 1)*ABUF + aloff]) = areg;
            __syncthreads();
        }

        // ---- K-combine: fold 8 slices -> 4 (tree == R3 bitwise) ----
        float* red = sh;
        if (kq >= 4){
            float* p = red + (kq - 4)*RSLICE + l5*LDW;
            #pragma unroll
            for (int bi = 0; bi < 8; ++bi){
                *(float4*)(p + (bi << 3))     = make_float4(acc0[bi][0], acc0[bi][1], acc0[bi][2], acc0[bi][3]);
                *(float4*)(p + (bi << 3) + 4) = make_float4(acc1[bi][0], acc1[bi][1], acc1[bi][2], acc1[bi][3]);
            }
        }
        __syncthreads();
        if (kq < 4){
            float* p = red + kq*RSLICE + l5*LDW;
            #pragma unroll
            for (int bi = 0; bi < 8; ++bi){
                float4 r0 = *(const float4*)(p + (bi << 3));
                float4 r1 = *(const float4*)(p + (bi << 3) + 4);
                acc0[bi][0] += r0.x; acc0[bi][1] += r0.y; acc0[bi][2] += r0.z; acc0[bi][3] += r0.w;
                acc1[bi][0] += r1.x; acc1[bi][1] += r1.y; acc1[bi][2] += r1.z; acc1[bi][3] += r1.w;
            }
            #pragma unroll
            for (int bi = 0; bi < 8; ++bi){
                *(float4*)(p + (bi << 3))     = make_float4(acc0[bi][0], acc0[bi][1], acc0[bi][2], acc0[bi][3]);
                *(float4*)(p + (bi << 3) + 4) = make_float4(acc1[bi][0], acc1[bi][1], acc1[bi][2], acc1[bi][3]);
            }
        }
        __syncthreads();

        // ---- epilogue: 256 threads x 2 cells (gate expressions frozen) ----
        {
            const int b  = tid >> 4;           // 0..15
            const int jh = tid & 15;
            const int ix = idx_lds[b];
            const int pos = ((b & 1) << 4) + jh;
            const int bi  = b >> 1;
            #pragma unroll
            for (int u = 0; u < 2; ++u){
                const int j = jh + (u << 4);                    // 0..31
                float g4[4];
                #pragma unroll
                for (int gg = 0; gg < 4; ++gg){
                    const int cell = (bi << 3) + (gg << 1) + u; // ri = 2g+u
                    float s  = red[           pos*LDW + cell];
                    s       += red[  RSLICE + pos*LDW + cell];
                    s       += red[2*RSLICE + pos*LDW + cell];
                    s       += red[3*RSLICE + pos*LDW + cell];
                    const int r = (gg << 9) + j0 + j;
                    g4[gg] = s + (Wih[r*Vn + ix] + bih[r] + bhh[r]);
                }
                const long bg = b0p + b;
                const int  jj = j0 + j;
                const float iv = sigf(g4[0]);
                const float fv = sigf(g4[1]);
                const float gv = tanhf(g4[2]);
                const float ov = sigf(g4[3]);
                const float cold = cws[bg*Hn + jj];
                const float cn2 = fv*cold + iv*gv;
                cws[bg*Hn + jj] = cn2;
                const float hn = ov * tanhf(cn2);
                hnext[bg*Hn + jj] = hn;
                hn_lds[b*33 + j] = hn;
            }
        }
        __syncthreads();

        // ---- partial logits: 16 partials x 32-j ascending (frozen) ----
        if (tid < 112){
            const float* wo = Wout + lg_v*Hn + j0;
            float s = 0.0f;
            #pragma unroll
            for (int jj = 0; jj < 32; ++jj)
                s = fmaf(hn_lds[lg_bl*33 + jj], wo[jj], s);
            atomicAdd(&lp[((long)(b0p + lg_bl)*Tn + t)*Vn + lg_v], s);
        }

        group_barrier(cnt, GBLK*(t+1));
    }

    // ---- GROUP-LOCAL finale: block (g,jt) owns batch row b0p+jt.
    //      All its inputs were written by group g (same XCD), synced by the
    //      final group_barrier. No cross-group reads -> no global wait. ----
    {
        const int bfin = b0p + jt;             // bijective over 0..511
        const long hb  = (long)bfin*Hn;
        out[NLP + hb + tid]        = hbuf[hb + tid];         // final h: buffer 0
        out[NLP + hb + tid + 256]  = hbuf[hb + tid + 256];
        out[NLP + BH + hb + tid]       = cws[hb + tid];
        out[NLP + BH + hb + tid + 256] = cws[hb + tid + 256];

        const long row = (long)bfin*Tn + tid;  // t = tid (256 steps)
        float x[Vn]; float m = -INFINITY;
        #pragma unroll
        for (int v = 0; v < Vn; ++v){ x[v] = lp[row*Vn + v] + bout[v]; m = fmaxf(m, x[v]); }
        float s = 0.0f;
        #pragma unroll
        for (int v = 0; v < Vn; ++v) s += expf(x[v] - m);
        const float ls = logf(s);
        #pragma unroll
        for (int v = 0; v < Vn; ++v) lp[row*Vn + v] = x[v] - m - ls;
    }
}

extern "C" void kernel_launch(void* const* d_in, const int* in_sizes, int n_in,
                              void* d_out, int out_size, void* d_ws, size_t ws_size,
                              hipStream_t stream) {
    const float* h0   = (const float*)d_in[0];
    const float* c0   = (const float*)d_in[1];
    const float* tgt  = (const float*)d_in[2];
    const float* Wih  = (const float*)d_in[3];
    const float* Whh  = (const float*)d_in[4];
    const float* bih  = (const float*)d_in[5];
    const float* bhh  = (const float*)d_in[6];
    const float* Wout = (const float*)d_in[7];
    const float* bout = (const float*)d_in[8];
    float* out = (float*)d_out;
    float* ws  = (float*)d_ws;               // 3*BH floats + counters
    int*   cnts = (int*)(ws + 3*BH);

    init_kernel<<<256, 256, 0, stream>>>(out, cnts);

    // NORMAL launch: 512 blocks x 256 thr, 2 blocks/CU static occupancy ->
    // all blocks resident; sync is hand-rolled atomic counters (agent scope).
    // (Cooperative launch rejects >256-block grids on this stack - R5/R6/R7
    // never executed; their "absmax 2.42" was a zeroed output buffer.)
    decoder_rnn_kernel<<<dim3(NBLK), dim3(NTHR), 0, stream>>>(
        h0, c0, tgt, Wih, Whh, bih, bhh, Wout, bout, out, ws);
}

// Round 9
// 6989.653 us; speedup vs baseline: 9.7735x; 1.1993x over previous
//
#include <hip/hip_runtime.h>
#include <hip/hip_bf16.h>
#include <math.h>

#define Bn 512
#define Tn 256
#define Hn 512
#define Vn 7
#define BH (Bn*Hn)          // 262144
#define NLP (Bn*Tn*Vn)      // 917504

#define NBLK 256            // 1 block/CU
#define NTHR 512
#define NGRP 16             // groups of 32 batch rows
#define GBLK 16             // blocks per group (j-tiles of width 32)
#define CNT_STRIDE 32

#define RST 132             // red row stride: 128 jg + 4 pad
#define REDH (32*RST)       // one K-half slab (32 b rows)

// Round-17: MFMA via triple-bf16 split. R8 killed the TLP theory (2 blocks/CU
// phase-lock and regress; absmax 0.0 proved order changes are safe). With fp32
// VALU FMA the floor is ~25-30us/step (FMA 6.8us + comparable staging). Exit:
// fp32 = bf16 hi+mid+lo; 6 cross-products (error ~2^-26*sum|hw| ~ 5e-8, 100x
// below the 5e-6 fp32-reorder scale that empirically never flips argmax) on
// mfma_f32_16x16x32_bf16 -> GEMM compute 0.8us/step. Fragments load DIRECTLY
// from global (A=hbuf fp32, W=Whh fp32, split in-register; lanes read 8
// contiguous floats = coalesced, L2-resident). No GEMM LDS, no staging
// barriers (4 syncs/step + group barrier). XCD-aware remap: same-XCD blocks
// share jt -> W working set 512KB/XCD. Wave (kh,gate): 32b x 32j x K-half.

typedef short short8 __attribute__((ext_vector_type(8)));
typedef float f32x4  __attribute__((ext_vector_type(4)));

__device__ __forceinline__ float sigf(float x){ return 1.0f/(1.0f + expf(-x)); }

__device__ __forceinline__ void bsplit(float x, short &h, short &m, short &l){
    __hip_bfloat16 bh = __float2bfloat16(x);
    float fh = __bfloat162float(bh);
    float r1 = x - fh;
    __hip_bfloat16 bm = __float2bfloat16(r1);
    float fm = __bfloat162float(bm);
    float r2 = r1 - fm;
    __hip_bfloat16 bl = __float2bfloat16(r2);
    h = __builtin_bit_cast(short, bh);
    m = __builtin_bit_cast(short, bm);
    l = __builtin_bit_cast(short, bl);
}

struct Trip { short8 h, m, l; };

__device__ __forceinline__ Trip split8(const float4 &a, const float4 &b){
    Trip t;
    const float v[8] = {a.x, a.y, a.z, a.w, b.x, b.y, b.z, b.w};
    #pragma unroll
    for (int e = 0; e < 8; ++e){
        short hh, mm, ll;
        bsplit(v[e], hh, mm, ll);
        t.h[e] = hh; t.m[e] = mm; t.l[e] = ll;
    }
    return t;
}

__device__ __forceinline__ void group_barrier(int* cnt, int target){
    __syncthreads();
    if (threadIdx.x == 0){
        __hip_atomic_fetch_add(cnt, 1, __ATOMIC_RELEASE, __HIP_MEMORY_SCOPE_AGENT);
        while (__hip_atomic_load(cnt, __ATOMIC_RELAXED, __HIP_MEMORY_SCOPE_AGENT) < target)
            __builtin_amdgcn_s_sleep(1);
        (void)__hip_atomic_load(cnt, __ATOMIC_ACQUIRE, __HIP_MEMORY_SCOPE_AGENT);
    }
    __syncthreads();
}

__global__ void init_kernel(float* lp, int* cnts){
    int i = blockIdx.x*blockDim.x + threadIdx.x;
    if (i < NGRP) cnts[i*CNT_STRIDE] = 0;
    for (int x = i; x < NLP; x += (int)(gridDim.x*blockDim.x)) lp[x] = 0.0f;
}

__global__ void __launch_bounds__(NTHR, 2)
decoder_rnn_kernel(const float* __restrict__ h0, const float* __restrict__ c0,
                   const float* __restrict__ tgt, const float* __restrict__ Wih,
                   const float* __restrict__ Whh, const float* __restrict__ bih,
                   const float* __restrict__ bhh, const float* __restrict__ Wout,
                   const float* __restrict__ bout, float* out, float* ws)
{
    __shared__ float red[2*32*RST];    // 33.8KB: [kh][b=32][jg=128(+4)]
    __shared__ float hn_lds[32*33];
    __shared__ int   idx_lds[32];

    float* hbuf = ws;                  // 2*BH ping-pong h
    float* cws  = ws + 2*BH;           // BH c-state
    int*   cnts = (int*)(ws + 3*BH);
    float* lp   = out;

    // XCD-aware remap: xcd = idx&7 -> jt = 2*xcd + idx[7]; bt = idx[6:3].
    // Same-XCD blocks share 2 jt panels (512KB W in 4MB L2); groups (bt)
    // span XCDs (cross-XCD group_barrier proven R3/R8).
    const int idx = blockIdx.x;
    const int jt  = ((idx & 7) << 1) | ((idx >> 7) & 1);
    const int bt  = (idx >> 3) & 15;
    const int b0  = bt << 5;
    const int j0  = jt << 5;

    const int tid  = threadIdx.x;
    const int wv   = tid >> 6;
    const int lane = tid & 63;
    const int kh   = wv & 1;           // K half (0/1)
    const int gp   = wv >> 1;          // gate owned by this wave pair (0..3)
    const int lr   = lane & 15;        // row-in-tile
    const int lk   = lane >> 4;        // k-group (0..3)
    int* cnt = cnts + bt*CNT_STRIDE;

    const int lg_bl = tid / 7, lg_v = tid % 7;

    // fragment global-address bases (t-invariant)
    long aoff0, aoff1, woff0, woff1;
    {
        const int kb = (kh << 8) + (lk << 3);
        aoff0 = (long)(b0 + lr)*Hn + kb;                 // A rows b0..b0+15
        aoff1 = aoff0 + (long)16*Hn;                     // A rows b0+16..31
        woff0 = (long)((gp << 9) + j0 + lr)*Hn + kb;     // W rows j0..j0+15 of gate gp
        woff1 = woff0 + (long)16*Hn;                     // W rows j0+16..31
    }

    // ---- per-block state init (R3 verbatim) ----
    #pragma unroll
    for (int i = 0; i < 8; ++i){
        const int f = tid + (i << 9);
        const int r = f >> 7, c4 = f & 127;
        *(float4*)(hbuf + (long)(b0 + r)*Hn + (c4 << 2)) =
            *(const float4*)(h0 + (long)(b0 + r)*Hn + (c4 << 2));
    }
    if (tid < 256){
        const int r = tid >> 3, c4 = tid & 7;
        *(float4*)(cws + (long)(b0 + r)*Hn + j0 + (c4 << 2)) =
            *(const float4*)(c0 + (long)(b0 + r)*Hn + j0 + (c4 << 2));
    }
    __syncthreads();

    for (int t = 0; t < Tn; ++t){
        const float* hprev = hbuf + (t & 1)*BH;
        float*       hnext = hbuf + ((t + 1) & 1)*BH;

        // ---- argmax -> one-hot index ----
        if (tid < 32){
            const int  bl = tid;
            const long b  = b0 + bl;
            float best; int am = 0;
            if (t == 0){
                const float* xp = tgt + (b*Tn)*Vn;
                best = xp[0];
                #pragma unroll
                for (int v = 1; v < Vn; ++v){ float xv = xp[v]; if (xv > best){ best = xv; am = v; } }
            } else {
                const float* xp = lp + (b*Tn + (t-1))*Vn;
                best = xp[0] + bout[0];
                #pragma unroll
                for (int v = 1; v < Vn; ++v){ float xv = xp[v] + bout[v]; if (xv > best){ best = xv; am = v; } }
            }
            idx_lds[bl] = am;
        }

        // ---- GEMM: 8 k-steps, fragments straight from global, no LDS ----
        f32x4 acc00 = {0.f,0.f,0.f,0.f}, acc01 = {0.f,0.f,0.f,0.f};
        f32x4 acc10 = {0.f,0.f,0.f,0.f}, acc11 = {0.f,0.f,0.f,0.f};
        float4 rA[2][2][2], rB[2][2][2];   // [buf][frag][half]

        rA[0][0][0] = *(const float4*)(hprev + aoff0);
        rA[0][0][1] = *(const float4*)(hprev + aoff0 + 4);
        rA[0][1][0] = *(const float4*)(hprev + aoff1);
        rA[0][1][1] = *(const float4*)(hprev + aoff1 + 4);
        rB[0][0][0] = *(const float4*)(Whh + woff0);
        rB[0][0][1] = *(const float4*)(Whh + woff0 + 4);
        rB[0][1][0] = *(const float4*)(Whh + woff1);
        rB[0][1][1] = *(const float4*)(Whh + woff1 + 4);

        #pragma unroll 2
        for (int ks = 0; ks < 8; ++ks){
            const int cb  = ks & 1, nb2 = cb ^ 1;
            const int kn  = (ks < 7) ? (ks + 1) : 7;   // clamped prefetch
            const int ko  = kn << 5;
            rA[nb2][0][0] = *(const float4*)(hprev + aoff0 + ko);
            rA[nb2][0][1] = *(const float4*)(hprev + aoff0 + ko + 4);
            rA[nb2][1][0] = *(const float4*)(hprev + aoff1 + ko);
            rA[nb2][1][1] = *(const float4*)(hprev + aoff1 + ko + 4);
            rB[nb2][0][0] = *(const float4*)(Whh + woff0 + ko);
            rB[nb2][0][1] = *(const float4*)(Whh + woff0 + ko + 4);
            rB[nb2][1][0] = *(const float4*)(Whh + woff1 + ko);
            rB[nb2][1][1] = *(const float4*)(Whh + woff1 + ko + 4);

            const Trip A0 = split8(rA[cb][0][0], rA[cb][0][1]);
            const Trip A1 = split8(rA[cb][1][0], rA[cb][1][1]);
            const Trip W0 = split8(rB[cb][0][0], rB[cb][0][1]);
            const Trip W1 = split8(rB[cb][1][0], rB[cb][1][1]);

            #define MM(ap, wp) \
                acc00 = __builtin_amdgcn_mfma_f32_16x16x32_bf16(A0.ap, W0.wp, acc00, 0,0,0); \
                acc01 = __builtin_amdgcn_mfma_f32_16x16x32_bf16(A0.ap, W1.wp, acc01, 0,0,0); \
                acc10 = __builtin_amdgcn_mfma_f32_16x16x32_bf16(A1.ap, W0.wp, acc10, 0,0,0); \
                acc11 = __builtin_amdgcn_mfma_f32_16x16x32_bf16(A1.ap, W1.wp, acc11, 0,0,0);
            MM(h,h) MM(h,m) MM(m,h) MM(h,l) MM(m,m) MM(l,h)
            #undef MM
        }

        // ---- park partials: red[kh][b][gp*32 + j]  (D: col=lane&15, row=(lane>>4)*4+reg) ----
        {
            float* rp = red + kh*REDH + (gp << 5) + lr;
            const int bb = lk << 2;
            #pragma unroll
            for (int r = 0; r < 4; ++r){
                rp[(bb + r)*RST]           = acc00[r];
                rp[(bb + r)*RST + 16]      = acc01[r];
                rp[(16 + bb + r)*RST]      = acc10[r];
                rp[(16 + bb + r)*RST + 16] = acc11[r];
            }
        }
        __syncthreads();

        // ---- epilogue: 512 threads x 2 cells; sum the 2 K-halves ----
        {
            const int b  = tid >> 4;
            const int jp = tid & 15;
            const int ix = idx_lds[b];
            float ga[4], gb_[4];
            #pragma unroll
            for (int g = 0; g < 4; ++g){
                const float2 v0 = *(const float2*)&red[       b*RST + (g << 5) + (jp << 1)];
                const float2 v1 = *(const float2*)&red[REDH + b*RST + (g << 5) + (jp << 1)];
                ga[g]  = v0.x + v1.x;
                gb_[g] = v0.y + v1.y;
            }
            #pragma unroll
            for (int u = 0; u < 2; ++u){
                const int j = (jp << 1) + u;
                float g4[4];
                #pragma unroll
                for (int g = 0; g < 4; ++g){
                    const int r = (g << 9) + j0 + j;
                    const float s = u ? gb_[g] : ga[g];
                    g4[g] = s + (Wih[r*Vn + ix] + bih[r] + bhh[r]);
                }
                const long bg = b0 + b;
                const int  jj = j0 + j;
                const float iv = sigf(g4[0]);
                const float fv = sigf(g4[1]);
                const float gv = tanhf(g4[2]);
                const float ov = sigf(g4[3]);
                const float cold = cws[bg*Hn + jj];
                const float cn2 = fv*cold + iv*gv;
                cws[bg*Hn + jj] = cn2;
                const float hn = ov * tanhf(cn2);
                hnext[bg*Hn + jj] = hn;
                hn_lds[b*33 + j] = hn;
            }
        }
        __syncthreads();

        // ---- partial logits: 16 partials x 32-j ascending ----
        if (tid < 224){
            const float* wo = Wout + lg_v*Hn + j0;
            float s = 0.0f;
            #pragma unroll
            for (int jj = 0; jj < 32; ++jj)
                s = fmaf(hn_lds[lg_bl*33 + jj], wo[jj], s);
            atomicAdd(&lp[((long)(b0 + lg_bl)*Tn + t)*Vn + lg_v], s);
        }

        group_barrier(cnt, GBLK*(t+1));
    }

    // ---- GROUP-LOCAL finale: block (bt,jt) owns batch rows b0+2*jt+{0,1}.
    //      All inputs written by group bt, synced by final group_barrier. ----
    {
        const int r0 = b0 + (jt << 1);
        #pragma unroll
        for (int rr = 0; rr < 2; ++rr){
            const long hb = (long)(r0 + rr)*Hn;
            out[NLP + hb + tid]      = hbuf[hb + tid];   // Tn even -> final h in buf 0
            out[NLP + BH + hb + tid] = cws[hb + tid];
        }
        const long row = (long)(r0 + (tid >> 8))*Tn + (tid & 255);
        float x[Vn]; float m = -INFINITY;
        #pragma unroll
        for (int v = 0; v < Vn; ++v){ x[v] = lp[row*Vn + v] + bout[v]; m = fmaxf(m, x[v]); }
        float s = 0.0f;
        #pragma unroll
        for (int v = 0; v < Vn; ++v) s += expf(x[v] - m);
        const float ls = logf(s);
        #pragma unroll
        for (int v = 0; v < Vn; ++v) lp[row*Vn + v] = x[v] - m - ls;
    }
}

extern "C" void kernel_launch(void* const* d_in, const int* in_sizes, int n_in,
                              void* d_out, int out_size, void* d_ws, size_t ws_size,
                              hipStream_t stream) {
    const float* h0   = (const float*)d_in[0];
    const float* c0   = (const float*)d_in[1];
    const float* tgt  = (const float*)d_in[2];
    const float* Wih  = (const float*)d_in[3];
    const float* Whh  = (const float*)d_in[4];
    const float* bih  = (const float*)d_in[5];
    const float* bhh  = (const float*)d_in[6];
    const float* Wout = (const float*)d_in[7];
    const float* bout = (const float*)d_in[8];
    float* out = (float*)d_out;
    float* ws  = (float*)d_ws;               // 3*BH floats + counters
    int*   cnts = (int*)(ws + 3*BH);

    init_kernel<<<256, 256, 0, stream>>>(out, cnts);

    // Normal launch (proven R8); sync via agent-scope atomic counters.
    decoder_rnn_kernel<<<dim3(NBLK), dim3(NTHR), 0, stream>>>(
        h0, c0, tgt, Wih, Whh, bih, bhh, Wout, bout, out, ws);
}

// Round 15
// 5579.539 us; speedup vs baseline: 12.2436x; 1.2527x over previous
//
#include <hip/hip_runtime.h>
#include <hip/hip_bf16.h>
#include <math.h>

#define Bn 512
#define Tn 256
#define Hn 512
#define Vn 7
#define BH (Bn*Hn)          // 262144
#define NLP (Bn*Tn*Vn)      // 917504

#define NBLK 256            // 1 block/CU
#define NTHR 512
#define NGRP 16             // groups of 32 batch rows
#define GBLK 16             // blocks per group (j-tiles of width 32)
#define CNT_STRIDE 32

#define RST 132             // red row stride: 128 jg + 4 pad
#define REDH (32*RST)       // one K-half slab

// Round-23: back to the R9 family. Empirical split after 14 rounds:
// acquire-barrier + plain-memory + atomicAdd-logits family = 6/6 PASS
// (R0-R3,R8,R9; two at absmax 0.0; three different step times, two different
// partial splits, two different GEMM arithmetics). sc0/sc1 + deterministic-
// logits family = 0/5, all by one bf16 bucket, across FIVE different logits
// arithmetics. Mechanism unidentified; the empirical rule is unambiguous.
// This round = R9 VERBATIM (sync, logits, epilogue, finale, init) with ONE
// in-family perf change: ring-4 DEPTH-2 prefetch in the GEMM k-loop
// (R9 was depth-1; post-invalidate L3 first-touch ~600-900cyc vs ~500cyc
// compute per k-step). unroll 4 keeps all ring indices static (rule #20);
// prefetch guard ks<6 is uniform + static after unroll.

typedef short short8 __attribute__((ext_vector_type(8)));
typedef float f32x4  __attribute__((ext_vector_type(4)));

__device__ __forceinline__ float sigf(float x){ return 1.0f/(1.0f + expf(-x)); }

__device__ __forceinline__ void bsplit(float x, short &h, short &m, short &l){
    __hip_bfloat16 bh = __float2bfloat16(x);
    float fh = __bfloat162float(bh);
    float r1 = x - fh;
    __hip_bfloat16 bm = __float2bfloat16(r1);
    float fm = __bfloat162float(bm);
    float r2 = r1 - fm;
    __hip_bfloat16 bl = __float2bfloat16(r2);
    h = __builtin_bit_cast(short, bh);
    m = __builtin_bit_cast(short, bm);
    l = __builtin_bit_cast(short, bl);
}

struct Trip { short8 h, m, l; };

__device__ __forceinline__ Trip split8(const float4 &a, const float4 &b){
    Trip t;
    const float v[8] = {a.x, a.y, a.z, a.w, b.x, b.y, b.z, b.w};
    #pragma unroll
    for (int e = 0; e < 8; ++e){
        short hh, mm, ll;
        bsplit(v[e], hh, mm, ll);
        t.h[e] = hh; t.m[e] = mm; t.l[e] = ll;
    }
    return t;
}

__device__ __forceinline__ void group_barrier(int* cnt, int target){
    __syncthreads();
    if (threadIdx.x == 0){
        __hip_atomic_fetch_add(cnt, 1, __ATOMIC_RELEASE, __HIP_MEMORY_SCOPE_AGENT);
        while (__hip_atomic_load(cnt, __ATOMIC_RELAXED, __HIP_MEMORY_SCOPE_AGENT) < target)
            __builtin_amdgcn_s_sleep(1);
        (void)__hip_atomic_load(cnt, __ATOMIC_ACQUIRE, __HIP_MEMORY_SCOPE_AGENT);
    }
    __syncthreads();
}

__global__ void init_kernel(float* lp, int* cnts){
    int i = blockIdx.x*blockDim.x + threadIdx.x;
    if (i < NGRP) cnts[i*CNT_STRIDE] = 0;
    for (int x = i; x < NLP; x += (int)(gridDim.x*blockDim.x)) lp[x] = 0.0f;
}

__global__ void __launch_bounds__(NTHR, 2)
decoder_rnn_kernel(const float* __restrict__ h0, const float* __restrict__ c0,
                   const float* __restrict__ tgt, const float* __restrict__ Wih,
                   const float* __restrict__ Whh, const float* __restrict__ bih,
                   const float* __restrict__ bhh, const float* __restrict__ Wout,
                   const float* __restrict__ bout, float* out, float* ws)
{
    __shared__ float red[2*32*RST];    // 33.8KB: [kh][b=32][jg=128(+4)]
    __shared__ float hn_lds[32*33];
    __shared__ int   idx_lds[32];

    float* hbuf = ws;                  // 2*BH ping-pong h
    float* cws  = ws + 2*BH;           // BH c-state
    int*   cnts = (int*)(ws + 3*BH);
    float* lp   = out;

    // XCD-aware remap (R9): same-XCD blocks share 2 jt panels.
    const int idx = blockIdx.x;
    const int jt  = ((idx & 7) << 1) | ((idx >> 7) & 1);
    const int bt  = (idx >> 3) & 15;
    const int b0  = bt << 5;
    const int j0  = jt << 5;

    const int tid  = threadIdx.x;
    const int wv   = tid >> 6;
    const int lane = tid & 63;
    const int kh   = wv & 1;           // K half (0/1)
    const int gp   = wv >> 1;          // gate owned by this wave pair (0..3)
    const int lr   = lane & 15;        // row-in-tile
    const int lk   = lane >> 4;        // k-group (0..3)
    int* cnt = cnts + bt*CNT_STRIDE;

    const int lg_bl = tid / 7, lg_v = tid % 7;

    // fragment global-address bases (t-invariant)
    long aoff0, aoff1, woff0, woff1;
    {
        const int kb = (kh << 8) + (lk << 3);
        aoff0 = (long)(b0 + lr)*Hn + kb;                 // A rows b0..b0+15
        aoff1 = aoff0 + (long)16*Hn;                     // A rows b0+16..31
        woff0 = (long)((gp << 9) + j0 + lr)*Hn + kb;     // W rows j0..j0+15 of gate gp
        woff1 = woff0 + (long)16*Hn;                     // W rows j0+16..31
    }

    // ---- per-block state init (R9 verbatim) ----
    #pragma unroll
    for (int i = 0; i < 8; ++i){
        const int f = tid + (i << 9);
        const int r = f >> 7, c4 = f & 127;
        *(float4*)(hbuf + (long)(b0 + r)*Hn + (c4 << 2)) =
            *(const float4*)(h0 + (long)(b0 + r)*Hn + (c4 << 2));
    }
    if (tid < 256){
        const int r = tid >> 3, c4 = tid & 7;
        *(float4*)(cws + (long)(b0 + r)*Hn + j0 + (c4 << 2)) =
            *(const float4*)(c0 + (long)(b0 + r)*Hn + j0 + (c4 << 2));
    }
    __syncthreads();

    for (int t = 0; t < Tn; ++t){
        const float* hprev = hbuf + (t & 1)*BH;
        float*       hnext = hbuf + ((t + 1) & 1)*BH;

        // ---- argmax -> one-hot index (R9 verbatim) ----
        if (tid < 32){
            const int  bl = tid;
            const long b  = b0 + bl;
            float best; int am = 0;
            if (t == 0){
                const float* xp = tgt + (b*Tn)*Vn;
                best = xp[0];
                #pragma unroll
                for (int v = 1; v < Vn; ++v){ float xv = xp[v]; if (xv > best){ best = xv; am = v; } }
            } else {
                const float* xp = lp + (b*Tn + (t-1))*Vn;
                best = xp[0] + bout[0];
                #pragma unroll
                for (int v = 1; v < Vn; ++v){ float xv = xp[v] + bout[v]; if (xv > best){ best = xv; am = v; } }
            }
            idx_lds[bl] = am;
        }

        // ---- GEMM: 8 k-steps, fragments from global, ring-4 DEPTH-2 prefetch ----
        f32x4 acc00 = {0.f,0.f,0.f,0.f}, acc01 = {0.f,0.f,0.f,0.f};
        f32x4 acc10 = {0.f,0.f,0.f,0.f}, acc11 = {0.f,0.f,0.f,0.f};
        float4 rA[4][2][2], rB[4][2][2];   // [ring][frag][half]

        #pragma unroll
        for (int p = 0; p < 2; ++p){        // prologue: ks=0 and ks=1
            const int ko = p << 5;
            rA[p][0][0] = *(const float4*)(hprev + aoff0 + ko);
            rA[p][0][1] = *(const float4*)(hprev + aoff0 + ko + 4);
            rA[p][1][0] = *(const float4*)(hprev + aoff1 + ko);
            rA[p][1][1] = *(const float4*)(hprev + aoff1 + ko + 4);
            rB[p][0][0] = *(const float4*)(Whh + woff0 + ko);
            rB[p][0][1] = *(const float4*)(Whh + woff0 + ko + 4);
            rB[p][1][0] = *(const float4*)(Whh + woff1 + ko);
            rB[p][1][1] = *(const float4*)(Whh + woff1 + ko + 4);
        }

        #pragma unroll 4
        for (int ks = 0; ks < 8; ++ks){
            const int cb = ks & 3;
            if (ks < 6){                    // depth-2 prefetch (static after unroll)
                const int nb2 = (ks + 2) & 3;
                const int ko  = (ks + 2) << 5;
                rA[nb2][0][0] = *(const float4*)(hprev + aoff0 + ko);
                rA[nb2][0][1] = *(const float4*)(hprev + aoff0 + ko + 4);
                rA[nb2][1][0] = *(const float4*)(hprev + aoff1 + ko);
                rA[nb2][1][1] = *(const float4*)(hprev + aoff1 + ko + 4);
                rB[nb2][0][0] = *(const float4*)(Whh + woff0 + ko);
                rB[nb2][0][1] = *(const float4*)(Whh + woff0 + ko + 4);
                rB[nb2][1][0] = *(const float4*)(Whh + woff1 + ko);
                rB[nb2][1][1] = *(const float4*)(Whh + woff1 + ko + 4);
            }

            const Trip A0 = split8(rA[cb][0][0], rA[cb][0][1]);
            const Trip A1 = split8(rA[cb][1][0], rA[cb][1][1]);
            const Trip W0 = split8(rB[cb][0][0], rB[cb][0][1]);
            const Trip W1 = split8(rB[cb][1][0], rB[cb][1][1]);

            #define MM(ap, wp) \
                acc00 = __builtin_amdgcn_mfma_f32_16x16x32_bf16(A0.ap, W0.wp, acc00, 0,0,0); \
                acc01 = __builtin_amdgcn_mfma_f32_16x16x32_bf16(A0.ap, W1.wp, acc01, 0,0,0); \
                acc10 = __builtin_amdgcn_mfma_f32_16x16x32_bf16(A1.ap, W0.wp, acc10, 0,0,0); \
                acc11 = __builtin_amdgcn_mfma_f32_16x16x32_bf16(A1.ap, W1.wp, acc11, 0,0,0);
            MM(h,h) MM(h,m) MM(m,h) MM(h,l) MM(m,m) MM(l,h)
            #undef MM
        }

        // ---- park partials (R9 verbatim) ----
        {
            float* rp = red + kh*REDH + (gp << 5) + lr;
            const int bb = lk << 2;
            #pragma unroll
            for (int r = 0; r < 4; ++r){
                rp[(bb + r)*RST]           = acc00[r];
                rp[(bb + r)*RST + 16]      = acc01[r];
                rp[(16 + bb + r)*RST]      = acc10[r];
                rp[(16 + bb + r)*RST + 16] = acc11[r];
            }
        }
        __syncthreads();

        // ---- epilogue: 512 threads x 2 cells (R9 verbatim) ----
        {
            const int b  = tid >> 4;
            const int jp = tid & 15;
            const int ix = idx_lds[b];
            float ga[4], gb_[4];
            #pragma unroll
            for (int g = 0; g < 4; ++g){
                const float2 v0 = *(const float2*)&red[       b*RST + (g << 5) + (jp << 1)];
                const float2 v1 = *(const float2*)&red[REDH + b*RST + (g << 5) + (jp << 1)];
                ga[g]  = v0.x + v1.x;
                gb_[g] = v0.y + v1.y;
            }
            #pragma unroll
            for (int u = 0; u < 2; ++u){
                const int j = (jp << 1) + u;
                float g4[4];
                #pragma unroll
                for (int g = 0; g < 4; ++g){
                    const int r = (g << 9) + j0 + j;
                    const float s = u ? gb_[g] : ga[g];
                    g4[g] = s + (Wih[r*Vn + ix] + bih[r] + bhh[r]);
                }
                const long bg = b0 + b;
                const int  jj = j0 + j;
                const float iv = sigf(g4[0]);
                const float fv = sigf(g4[1]);
                const float gv = tanhf(g4[2]);
                const float ov = sigf(g4[3]);
                const float cold = cws[bg*Hn + jj];
                const float cn2 = fv*cold + iv*gv;
                cws[bg*Hn + jj] = cn2;
                const float hn = ov * tanhf(cn2);
                hnext[bg*Hn + jj] = hn;
                hn_lds[b*33 + j] = hn;
            }
        }
        __syncthreads();

        // ---- partial logits: 16 partials x 32-j ascending, atomicAdd (R9 verbatim) ----
        if (tid < 224){
            const float* wo = Wout + lg_v*Hn + j0;
            float s = 0.0f;
            #pragma unroll
            for (int jj = 0; jj < 32; ++jj)
                s = fmaf(hn_lds[lg_bl*33 + jj], wo[jj], s);
            atomicAdd(&lp[((long)(b0 + lg_bl)*Tn + t)*Vn + lg_v], s);
        }

        group_barrier(cnt, GBLK*(t+1));
    }

    // ---- GROUP-LOCAL finale (R9 verbatim): block (bt,jt) owns rows b0+2jt+{0,1} ----
    {
        const int r0 = b0 + (jt << 1);
        #pragma unroll
        for (int rr = 0; rr < 2; ++rr){
            const long hb = (long)(r0 + rr)*Hn;
            out[NLP + hb + tid]      = hbuf[hb + tid];   // Tn even -> final h in buf 0
            out[NLP + BH + hb + tid] = cws[hb + tid];
        }
        const long row = (long)(r0 + (tid >> 8))*Tn + (tid & 255);
        float x[Vn]; float m = -INFINITY;
        #pragma unroll
        for (int v = 0; v < Vn; ++v){ x[v] = lp[row*Vn + v] + bout[v]; m = fmaxf(m, x[v]); }
        float s = 0.0f;
        #pragma unroll
        for (int v = 0; v < Vn; ++v) s += expf(x[v] - m);
        const float ls = logf(s);
        #pragma unroll
        for (int v = 0; v < Vn; ++v) lp[row*Vn + v] = x[v] - m - ls;
    }
}

extern "C" void kernel_launch(void* const* d_in, const int* in_sizes, int n_in,
                              void* d_out, int out_size, void* d_ws, size_t ws_size,
                              hipStream_t stream) {
    const float* h0   = (const float*)d_in[0];
    const float* c0   = (const float*)d_in[1];
    const float* tgt  = (const float*)d_in[2];
    const float* Wih  = (const float*)d_in[3];
    const float* Whh  = (const float*)d_in[4];
    const float* bih  = (const float*)d_in[5];
    const float* bhh  = (const float*)d_in[6];
    const float* Wout = (const float*)d_in[7];
    const float* bout = (const float*)d_in[8];
    float* out = (float*)d_out;
    float* ws  = (float*)d_ws;               // 3*BH floats + counters
    int*   cnts = (int*)(ws + 3*BH);

    init_kernel<<<256, 256, 0, stream>>>(out, cnts);

    decoder_rnn_kernel<<<dim3(NBLK), dim3(NTHR), 0, stream>>>(
        h0, c0, tgt, Wih, Whh, bih, bhh, Wout, bout, out, ws);
}